// Round 1
// 26578.671 us; speedup vs baseline: 1.4341x; 1.4341x over previous
//
#include <hip/hip_runtime.h>
#include <math.h>

// B=128, T=256, H=E=1024, L=2, EOS=1
#define NB 128
#define NT 256
#define NH 1024
#define NE 1024
#define G4 4096
#define EOSL 1

// ---------------- workspace layout (float units) ----------------
// zp  [8ks][2dir][4096][128] = 8,388,608
// c   [(l*2+dir)][1024][128] =   524,288
// Ht  [2dir][1024][128]      =   262,144
// fcz [16][128][1024]        = 2,097,152
// bias[(l*2+dir)][4096]      =    16,384
// ended 128 int
// XPH packed h frags: 2dir x 64ktile x 8btile x 2KB = 2MB (524,288 f)
// XPX packed x frags: 32ktile x 8btile x 2KB = 512KB (131,072 f)
#define ZP_OFF   ((size_t)0)
#define C_OFF    ((size_t)8388608)
#define HT_OFF   ((size_t)8912896)
#define FCZ_OFF  ((size_t)9175040)
#define BIAS_OFF ((size_t)11272192)
#define END_OFF  ((size_t)11288576)
#define XPH_OFF  ((size_t)11288704)
#define XPX_OFF  ((size_t)11812992)
#define TOTAL_F  ((size_t)11944064)   // ~47.8 MB

typedef __attribute__((ext_vector_type(8))) short s8v;   // 8 bf16 for MFMA A/B
typedef __attribute__((ext_vector_type(4))) float f4v;   // MFMA C/D

struct GMF {
  const float* W[16];            // [dir*8+ks] fp32 weights, row stride 1024, pre-col-offset
  const unsigned short* Bp[16];  // [dir*8+ks] packed activation frag base (hi; lo at +512 shorts)
};

__device__ __forceinline__ void add4(float4& d, const float4 a) {
  d.x += a.x; d.y += a.y; d.z += a.z; d.w += a.w;
}
__device__ __forceinline__ float sigmoid_stable(float x) {
  if (x >= 0.f) return 1.f / (1.f + expf(-x));
  float ex = expf(x);
  return ex / (1.f + ex);
}
// fp32 -> bf16(RNE) hi + bf16(RNE) lo;  hi+lo captures ~16 mantissa bits (rel err ~2^-18)
__device__ __forceinline__ unsigned short bf_rne(float x) {
  unsigned u = __float_as_uint(x);
  return (unsigned short)((u + 0x7FFFu + ((u >> 16) & 1u)) >> 16);
}
__device__ __forceinline__ void split_bf(float x, unsigned short& h, unsigned short& l) {
  unsigned u = __float_as_uint(x);
  unsigned hb = (u + 0x7FFFu + ((u >> 16) & 1u)) >> 16;
  h = (unsigned short)hb;
  float r = x - __uint_as_float(hb << 16);   // exact
  l = bf_rne(r);
}

// packed activation frag layout (B operand of mfma_f32_16x16x32_bf16):
//   frag = [ktile][btile]: 2048 B = 64 lanes x {16B hi, then 16B lo at +1024B}
//   element (k,b): lane = (b&15) + 16*((k>>3)&3), reg = k&7
//   -> reader: lane l holds B[k=(l>>4)*8+r][j=l&15]  (exact mfma B layout)

// ---------------- init: pack h state + x0, c, fused bias, ended ----------------
__global__ void k_init(const int* yy, const float* h_t, const float* h_tr,
                       const float* c0, const float* c0r,
                       const float* b_ih, const float* b_hh,
                       const float* b_ihr, const float* b_hhr,
                       const float* emb,
                       unsigned short* xph, unsigned short* xpx,
                       float* call, float* bias, int* ended)
{
  int idx = blockIdx.x * 256 + threadIdx.x;   // 2048 blocks -> 524288
  if (idx < 2 * 2048 * 128) {                 // XPH: row = l*1024+n -> ktile = row>>5 (h0:0..31, h1:32..63)
    int dir = idx / (2048 * 128); int rem = idx % (2048 * 128);
    int row = rem >> 7, b = rem & 127;
    int l = row >> 10, n = row & 1023;
    const float* src = dir ? h_tr : h_t;
    float v = src[((size_t)l * 128 + b) * 1024 + n];
    unsigned short h, lo; split_bf(v, h, lo);
    size_t off = ((size_t)(dir * 64 + (row >> 5)) * 8 + (b >> 4)) * 1024
               + ((b & 15) + 16 * ((n >> 3) & 3)) * 8 + (n & 7);
    xph[off] = h; xph[off + 512] = lo;
  }
  if (idx < 4 * 1024 * 128) {                 // c[(l*2+dir)][n][b]
    int ld = idx / (1024 * 128); int l = ld >> 1, dir = ld & 1;
    int rem = idx % (1024 * 128); int n = rem >> 7;
    call[idx] = (dir ? c0r : c0)[l * 1024 + n];
  }
  if (idx < 4 * 4096) {                       // bias[(l*2+dir)][m]
    int ld = idx / 4096; int l = ld >> 1, dir = ld & 1;
    int m = idx & 4095;
    bias[idx] = (dir ? b_ihr : b_ih)[l * 4096 + m] + (dir ? b_hhr : b_hh)[l * 4096 + m];
  }
  if (idx < 128 * 1024) {                     // XPX: x0 = emb[yy[:,0]]
    int b = idx >> 10, k = idx & 1023;
    int e = yy[b * NT];
    float v = emb[(size_t)e * 1024 + k];
    unsigned short h, lo; split_bf(v, h, lo);
    size_t off = ((size_t)(k >> 5) * 8 + (b >> 4)) * 1024
               + ((b & 15) + 16 * ((k >> 3) & 3)) * 8 + (k & 7);
    xpx[off] = h; xpx[off + 512] = lo;
  }
  if (idx < NB) ended[idx] = 0;
}

// ---------------- main cell GEMM via split-bf16 MFMA ----------------
// z[m=4096][b=128] = W[m][K=2048] * X[K][b], K-split 8 (BK=256) -> zp partials.
// Block: 512 thr = 8 waves (4 wm x 2 wb); wave = 64m x 64b = 4x4 mfma tiles.
// W fp32 loaded global->reg, split hi/lo in-reg (same bytes as fp32, no LDS, no barriers).
// X read pre-packed (hi/lo planes) in exact B-frag lane order.
__device__ __forceinline__ void loadk(const float* Wb, const unsigned short* Bb, int kk,
                                      float4 (&a)[4][2], s8v (&bh)[4], s8v (&bl)[4])
{
  #pragma unroll
  for (int mt = 0; mt < 4; mt++) {
    a[mt][0] = *(const float4*)(Wb + (size_t)mt * 16384 + kk * 32);
    a[mt][1] = *(const float4*)(Wb + (size_t)mt * 16384 + kk * 32 + 4);
  }
  #pragma unroll
  for (int bt = 0; bt < 4; bt++) {
    bh[bt] = *(const s8v*)(Bb + (size_t)(kk * 8 + bt) * 1024);
    bl[bt] = *(const s8v*)(Bb + (size_t)(kk * 8 + bt) * 1024 + 512);
  }
}
__device__ __forceinline__ void cvt8(float4 a0, float4 a1, s8v& hi, s8v& lo)
{
  const float v[8] = {a0.x, a0.y, a0.z, a0.w, a1.x, a1.y, a1.z, a1.w};
  #pragma unroll
  for (int j = 0; j < 8; j++) {
    unsigned short h, l; split_bf(v[j], h, l);
    hi[j] = (short)h; lo[j] = (short)l;
  }
}

__global__ __launch_bounds__(512, 2) void k_gemm(GMF d, float* zp)
{
  const int mt0 = blockIdx.x, ks = blockIdx.y, dir = blockIdx.z;
  const int tid = threadIdx.x, l = tid & 63, w = tid >> 6;
  const int wm = w >> 1, wb = w & 1;
  const int m0 = mt0 * 256 + wm * 64;
  const int lr = l & 15, lk = l >> 4;
  const float* Wb = d.W[dir * 8 + ks] + (size_t)(m0 + lr) * 1024 + lk * 8;
  const unsigned short* Bb = d.Bp[dir * 8 + ks] + (size_t)(wb * 4) * 1024 + l * 8;

  f4v acc[4][4];
  #pragma unroll
  for (int mt = 0; mt < 4; mt++)
    #pragma unroll
    for (int bt = 0; bt < 4; bt++)
      acc[mt][bt] = (f4v)(0.0f);

  float4 a[4][2]; s8v bh[4], bl[4];
  loadk(Wb, Bb, 0, a, bh, bl);
  #pragma unroll 1
  for (int kk = 0; kk < 8; kk++) {
    float4 a2[4][2]; s8v bh2[4], bl2[4];
    if (kk < 7) loadk(Wb, Bb, kk + 1, a2, bh2, bl2);   // prefetch next k-chunk
    #pragma unroll
    for (int mt = 0; mt < 4; mt++) {
      s8v wh, wl;
      cvt8(a[mt][0], a[mt][1], wh, wl);
      #pragma unroll
      for (int bt = 0; bt < 4; bt++) {
        acc[mt][bt] = __builtin_amdgcn_mfma_f32_16x16x32_bf16(wh, bh[bt], acc[mt][bt], 0, 0, 0);
        acc[mt][bt] = __builtin_amdgcn_mfma_f32_16x16x32_bf16(wh, bl[bt], acc[mt][bt], 0, 0, 0);
        acc[mt][bt] = __builtin_amdgcn_mfma_f32_16x16x32_bf16(wl, bh[bt], acc[mt][bt], 0, 0, 0);
      }
    }
    if (kk < 7) {
      #pragma unroll
      for (int mt = 0; mt < 4; mt++) { a[mt][0] = a2[mt][0]; a[mt][1] = a2[mt][1]; }
      #pragma unroll
      for (int bt = 0; bt < 4; bt++) { bh[bt] = bh2[bt]; bl[bt] = bl2[bt]; }
    }
  }
  // C/D layout: row=(lane>>4)*4+reg, col=lane&15
  float* zb = zp + (size_t)(ks * 2 + dir) * 4096 * 128;
  #pragma unroll
  for (int mt = 0; mt < 4; mt++)
    #pragma unroll
    for (int bt = 0; bt < 4; bt++) {
      int m = m0 + mt * 16 + lk * 4;
      int b = wb * 64 + bt * 16 + lr;
      #pragma unroll
      for (int r = 0; r < 4; r++)
        zb[(size_t)(m + r) * 128 + b] = acc[mt][bt][r];
    }
}

// ---------------- gates: sum 8 zp partials + bias -> h, c; pack h hi/lo frags ----------------
__global__ void k_gates(const float* zp, const float* bias, float* c,
                        unsigned short* xph, int ktile0, float* hB)
{
  int t = threadIdx.x;
  int idx = blockIdx.x * 256 + t;
  int n = idx >> 5, cc = (idx & 31) << 2;
  int dir = blockIdx.y;
  float4 g[4];
  #pragma unroll
  for (int gg = 0; gg < 4; gg++) {
    int row = gg * 1024 + n;
    float4 s = *(const float4*)(zp + ((size_t)dir * 4096 + row) * 128 + cc);
    #pragma unroll
    for (int ksx = 1; ksx < 8; ksx++)
      add4(s, *(const float4*)(zp + ((size_t)(ksx * 2 + dir) * 4096 + row) * 128 + cc));
    float b = bias[dir * 4096 + row];
    s.x += b; s.y += b; s.z += b; s.w += b;
    g[gg] = s;
  }
  float* cp = c + ((size_t)dir * 1024 + n) * 128 + cc;
  float4 cold = *(float4*)cp;
  float4 cn, hn;
  cn.x = sigmoid_stable(g[1].x) * cold.x + sigmoid_stable(g[0].x) * tanhf(g[2].x);
  cn.y = sigmoid_stable(g[1].y) * cold.y + sigmoid_stable(g[0].y) * tanhf(g[2].y);
  cn.z = sigmoid_stable(g[1].z) * cold.z + sigmoid_stable(g[0].z) * tanhf(g[2].z);
  cn.w = sigmoid_stable(g[1].w) * cold.w + sigmoid_stable(g[0].w) * tanhf(g[2].w);
  hn.x = sigmoid_stable(g[3].x) * tanhf(cn.x);
  hn.y = sigmoid_stable(g[3].y) * tanhf(cn.y);
  hn.z = sigmoid_stable(g[3].z) * tanhf(cn.z);
  hn.w = sigmoid_stable(g[3].w) * tanhf(cn.w);
  *(float4*)cp = cn;
  // pack hn into XPH frags (4 consecutive b, same frag)
  size_t fo = ((size_t)(dir * 64 + ktile0 + (n >> 5)) * 8 + (cc >> 4)) * 1024
            + ((cc & 15) + 16 * ((n >> 3) & 3)) * 8 + (n & 7);
  const float* hv = &hn.x;
  #pragma unroll
  for (int j = 0; j < 4; j++) {
    unsigned short h, lo; split_bf(hv[j], h, lo);
    xph[fo + j * 8] = h;
    xph[fo + j * 8 + 512] = lo;
  }
  if (hB)
    *(float4*)(hB + (size_t)dir * (1024 * 128) + (size_t)n * 128 + cc) = hn;
}

// ---------------- FC GEMM (fp32): fcz[kp][b][e] partials of wh @ fc_W.T ----------------
__global__ __launch_bounds__(256) void k_fc(const float* Ht, const float* fc_W, float* fcz)
{
  int et = blockIdx.x, kp = blockIdx.y;
  int e0 = et * 64;
  int k00 = kp * 128;
  __shared__ __align__(16) float in_s[128][36];
  __shared__ __align__(16) float w_s[64][36];
  int t = threadIdx.x, e_sub = t & 7, bg = t >> 3, b0 = bg * 4;
  float acc[8][4] = {};
  for (int kc = 0; kc < 128; kc += 32) {
    #pragma unroll
    for (int i = 0; i < 4; i++) {
      int flat = t + 256 * i, r = flat >> 3, f4i = flat & 7;
      const float* row = Ht + (r >= 64 ? (size_t)NH * NB + (size_t)(r - 64) * 2048
                                       : (size_t)r * 2048);
      float4 v = *(const float4*)(row + k00 + kc + f4i * 4);
      int sw = (f4i ^ (r >> 2)) & 7;
      *(float4*)&in_s[r][sw * 4] = v;
    }
    #pragma unroll
    for (int i = 0; i < 2; i++) {
      int flat = t + 256 * i, r = flat >> 3, f4i = flat & 7;
      *(float4*)&w_s[r][f4i * 4] =
          *(const float4*)(fc_W + (size_t)(e0 + r) * 2048 + k00 + kc + f4i * 4);
    }
    __syncthreads();
    #pragma unroll
    for (int kq = 0; kq < 8; kq++) {
      int ksw = (kq ^ bg) & 7;
      float4 a4[4];
      #pragma unroll
      for (int ib = 0; ib < 4; ib++) a4[ib] = *(const float4*)&in_s[b0 + ib][ksw * 4];
      float4 w4[8];
      #pragma unroll
      for (int je = 0; je < 8; je++) w4[je] = *(const float4*)&w_s[e_sub + 8 * je][kq * 4];
      #pragma unroll
      for (int je = 0; je < 8; je++)
        #pragma unroll
        for (int ib = 0; ib < 4; ib++)
          acc[je][ib] += a4[ib].x * w4[je].x + a4[ib].y * w4[je].y +
                         a4[ib].z * w4[je].z + a4[ib].w * w4[je].w;
    }
    __syncthreads();
  }
  for (int je = 0; je < 8; je++) {
    int e = e0 + e_sub + 8 * je;
    for (int ib = 0; ib < 4; ib++)
      fcz[((size_t)kp * NB + b0 + ib) * NE + e] = acc[je][ib];
  }
}

// ---------------- finalize: logits, override, argmax, pack next x, softmax ----------------
__global__ void k_final(const float* fcz, const float* fc_b, int* ended,
                        float* out, int tstep, const float* emb, unsigned short* xpx)
{
  int b = blockIdx.x;
  int t = threadIdx.x;
  __shared__ float sval[256];
  __shared__ int   sidx[256];
  __shared__ float ssum[256];
  bool end = (ended[b] != 0);
  float v[4];
  int e_base = t * 4;
  #pragma unroll
  for (int j = 0; j < 4; j++) {
    int e = e_base + j;
    float s = fc_b[e];
    #pragma unroll
    for (int p = 0; p < 16; p++) s += fcz[((size_t)p * NB + b) * NE + e];
    v[j] = end ? (e == EOSL ? 1.f : 0.f) : s;
  }
  float bv = v[0]; int bi = e_base;
  #pragma unroll
  for (int j = 1; j < 4; j++) if (v[j] > bv) { bv = v[j]; bi = e_base + j; }
  sval[t] = bv; sidx[t] = bi;
  __syncthreads();
  for (int s = 128; s > 0; s >>= 1) {
    if (t < s) {
      float ov = sval[t + s]; int oi = sidx[t + s];
      if (ov > sval[t] || (ov == sval[t] && oi < sidx[t])) { sval[t] = ov; sidx[t] = oi; }
    }
    __syncthreads();
  }
  float m = sval[0]; int label = sidx[0];
  // pack next-step x = emb[label] into XPX (hi/lo bf16 frags)
  {
    int k0 = t * 4;
    float4 e4 = *(const float4*)(emb + (size_t)label * 1024 + k0);
    size_t off = ((size_t)(k0 >> 5) * 8 + (b >> 4)) * 1024
               + ((b & 15) + 16 * ((k0 >> 3) & 3)) * 8 + (k0 & 7);
    ushort4 h4, l4;
    unsigned short hh, ll;
    split_bf(e4.x, hh, ll); h4.x = hh; l4.x = ll;
    split_bf(e4.y, hh, ll); h4.y = hh; l4.y = ll;
    split_bf(e4.z, hh, ll); h4.z = hh; l4.z = ll;
    split_bf(e4.w, hh, ll); h4.w = hh; l4.w = ll;
    *(ushort4*)(xpx + off) = h4;
    *(ushort4*)(xpx + off + 512) = l4;
  }
  float ls = 0.f;
  #pragma unroll
  for (int j = 0; j < 4; j++) { v[j] = expf(v[j] - m); ls += v[j]; }
  ssum[t] = ls;
  __syncthreads();
  for (int s = 128; s > 0; s >>= 1) { if (t < s) ssum[t] += ssum[t + s]; __syncthreads(); }
  float inv = 1.f / ssum[0];
  float* orow = out + ((size_t)b * NT + tstep) * NE + e_base;
  #pragma unroll
  for (int j = 0; j < 4; j++) orow[j] = v[j] * inv;
  if (t == 0) ended[b] = (end || label == EOSL) ? 1 : 0;
}

extern "C" void kernel_launch(void* const* d_in, const int* in_sizes, int n_in,
                              void* d_out, int out_size, void* d_ws, size_t ws_size,
                              hipStream_t stream)
{
  const int*   yy    = (const int*)d_in[0];
  const float* h_t   = (const float*)d_in[1];
  const float* h_tr  = (const float*)d_in[2];
  const float* emb   = (const float*)d_in[4];
  const float* W_ih  = (const float*)d_in[5];
  const float* W_hh  = (const float*)d_in[6];
  const float* b_ih  = (const float*)d_in[7];
  const float* b_hh  = (const float*)d_in[8];
  const float* W_ihr = (const float*)d_in[9];
  const float* W_hhr = (const float*)d_in[10];
  const float* b_ihr = (const float*)d_in[11];
  const float* b_hhr = (const float*)d_in[12];
  const float* c0    = (const float*)d_in[13];
  const float* c0r   = (const float*)d_in[14];
  const float* fc_W  = (const float*)d_in[15];
  const float* fc_b  = (const float*)d_in[16];
  float* out = (float*)d_out;

  float* ws   = (float*)d_ws;
  float* zp   = ws + ZP_OFF;
  float* call = ws + C_OFF;
  float* Ht   = ws + HT_OFF;
  float* fcz  = ws + FCZ_OFF;
  float* bias = ws + BIAS_OFF;
  int* ended  = (int*)(ws + END_OFF);
  unsigned short* xph = (unsigned short*)(ws + XPH_OFF);
  unsigned short* xpx = (unsigned short*)(ws + XPX_OFF);

  k_init<<<2048, 256, 0, stream>>>(yy, h_t, h_tr, c0, c0r, b_ih, b_hh, b_ihr, b_hhr,
                                   emb, xph, xpx, call, bias, ended);

  GMF d0, d1;
  for (int dir = 0; dir < 2; dir++) {
    const float* Wih0 = dir ? W_ihr : W_ih;
    const float* Whh0 = dir ? W_hhr : W_hh;
    const float* Wih1 = Wih0 + (size_t)G4 * NH;
    const float* Whh1 = Whh0 + (size_t)G4 * NH;
    for (int ks = 0; ks < 8; ks++) {
      // layer0 input: k 0..1023 = x (Wih0, XPX shared across dir), k 1024..2047 = h0 (Whh0, XPH kt 0..31)
      d0.W[dir * 8 + ks]  = (ks < 4) ? (Wih0 + ks * 256) : (Whh0 + (ks - 4) * 256);
      d0.Bp[dir * 8 + ks] = (ks < 4) ? (xpx + (size_t)(ks * 64) * 1024)
                                     : (xph + (size_t)((dir * 64 + (ks - 4) * 8) * 8) * 1024);
      // layer1 input: k 0..1023 = h0 (Wih1, XPH kt 0..31), k 1024..2047 = h1 (Whh1, XPH kt 32..63)
      d1.W[dir * 8 + ks]  = (ks < 4) ? (Wih1 + ks * 256) : (Whh1 + (ks - 4) * 256);
      d1.Bp[dir * 8 + ks] = xph + (size_t)((dir * 64 + ks * 8) * 8) * 1024;
    }
  }

  for (int t = 0; t < NT; t++) {
    k_gemm<<<dim3(16, 8, 2), 512, 0, stream>>>(d0, zp);
    k_gates<<<dim3(128, 2), 256, 0, stream>>>(zp, bias, call, xph, 0, nullptr);
    k_gemm<<<dim3(16, 8, 2), 512, 0, stream>>>(d1, zp);
    k_gates<<<dim3(128, 2), 256, 0, stream>>>(zp, bias + 2 * 4096,
                                              call + (size_t)2 * 1024 * 128, xph, 32, Ht);
    k_fc<<<dim3(16, 16), 256, 0, stream>>>(Ht, fc_W, fcz);
    k_final<<<128, 256, 0, stream>>>(fcz, fc_b, ended, out, t, emb, xpx);
  }
}

// Round 3
// 23954.518 us; speedup vs baseline: 1.5912x; 1.1095x over previous
//
#include <hip/hip_runtime.h>
#include <math.h>

// B=128, T=256, H=E=1024, L=2, EOS=1
#define NB 128
#define NT 256
#define NH 1024
#define NE 1024
#define G4 4096
#define EOSL 1

// ---------------- workspace layout (float units) ----------------
// z   [2dir][4096][128]                 = 1,048,576  (single-written per gemm)
// c   [(l*2+dir)][1024][128]            =   524,288
// Ht  [2dir][1024][128]                 =   262,144
// fcz [8][128][1024]                    = 1,048,576
// bias[(l*2+dir)][4096]                 =    16,384
// ended 128
// xph packed h frags  (2 MB)            =   524,288
// xpx packed x frags  (0.5 MB)          =   131,072
// WP  packed weights [4ld][256mt][64kt][1024sh] = 67,108,864 shorts = 33,554,432 f
#define Z_OFF    ((size_t)0)
#define C_OFF    ((size_t)1048576)
#define HT_OFF   ((size_t)1572864)
#define FCZ_OFF  ((size_t)1835008)
#define BIAS_OFF ((size_t)2883584)
#define END_OFF  ((size_t)2899968)
#define XPH_OFF  ((size_t)2900096)
#define XPX_OFF  ((size_t)3424384)
#define WP_OFF   ((size_t)3555456)
#define TOTAL_MIN_F  ((size_t)3555456)
#define TOTAL_PACK_F ((size_t)37109888)   // ~148.4 MB

typedef __attribute__((ext_vector_type(8))) short s8v;   // 8 bf16 for MFMA A/B
typedef __attribute__((ext_vector_type(4))) float f4v;   // MFMA C/D

struct GMF {
  const float* W[16];            // [dir*8+ks] fp32 weights (fallback path)
  const unsigned short* Bp[16];  // [dir*8+ks] packed activation frags (hi; lo at +512)
  const unsigned short* Wp[2];   // [dir] packed weight frags for this layer (PACKED path)
};

__device__ __forceinline__ void add4(float4& d, const float4 a) {
  d.x += a.x; d.y += a.y; d.z += a.z; d.w += a.w;
}
__device__ __forceinline__ float sigmoid_stable(float x) {
  if (x >= 0.f) return 1.f / (1.f + expf(-x));
  float ex = expf(x);
  return ex / (1.f + ex);
}
__device__ __forceinline__ unsigned short bf_rne(float x) {
  unsigned u = __float_as_uint(x);
  return (unsigned short)((u + 0x7FFFu + ((u >> 16) & 1u)) >> 16);
}
__device__ __forceinline__ void split_bf(float x, unsigned short& h, unsigned short& l) {
  unsigned u = __float_as_uint(x);
  unsigned hb = (u + 0x7FFFu + ((u >> 16) & 1u)) >> 16;
  h = (unsigned short)hb;
  float r = x - __uint_as_float(hb << 16);   // exact
  l = bf_rne(r);
}
__device__ __forceinline__ void cvt8(float4 a0, float4 a1, s8v& hi, s8v& lo)
{
  const float v[8] = {a0.x, a0.y, a0.z, a0.w, a1.x, a1.y, a1.z, a1.w};
  #pragma unroll
  for (int j = 0; j < 8; j++) {
    unsigned short h, l; split_bf(v[j], h, l);
    hi[j] = (short)h; lo[j] = (short)l;
  }
}

// frag layouts (verified rounds 0-1):
//  B (acts): lane l holds B[k=(l>>4)*8+r][b=l&15]; frag = 512 hi shorts + 512 lo shorts
//  A (wgts): lane l holds A[m=l&15][k=(l>>4)*8+r]; same hi/lo plane structure

// ---------------- init: pack h state + x0, c, fused bias, ended ----------------
__global__ void k_init(const int* yy, const float* h_t, const float* h_tr,
                       const float* c0, const float* c0r,
                       const float* b_ih, const float* b_hh,
                       const float* b_ihr, const float* b_hhr,
                       const float* emb,
                       unsigned short* xph, unsigned short* xpx,
                       float* call, float* bias, int* ended)
{
  int idx = blockIdx.x * 256 + threadIdx.x;   // 2048 blocks -> 524288
  if (idx < 2 * 2048 * 128) {                 // XPH
    int dir = idx / (2048 * 128); int rem = idx % (2048 * 128);
    int row = rem >> 7, b = rem & 127;
    int l = row >> 10, n = row & 1023;
    const float* src = dir ? h_tr : h_t;
    float v = src[((size_t)l * 128 + b) * 1024 + n];
    unsigned short h, lo; split_bf(v, h, lo);
    size_t off = ((size_t)(dir * 64 + (row >> 5)) * 8 + (b >> 4)) * 1024
               + ((b & 15) + 16 * ((n >> 3) & 3)) * 8 + (n & 7);
    xph[off] = h; xph[off + 512] = lo;
  }
  if (idx < 4 * 1024 * 128) {                 // c[(l*2+dir)][n][b]
    int ld = idx / (1024 * 128); int l = ld >> 1, dir = ld & 1;
    int rem = idx % (1024 * 128); int n = rem >> 7;
    call[idx] = (dir ? c0r : c0)[l * 1024 + n];
  }
  if (idx < 4 * 4096) {                       // bias[(l*2+dir)][m]
    int ld = idx / 4096; int l = ld >> 1, dir = ld & 1;
    int m = idx & 4095;
    bias[idx] = (dir ? b_ihr : b_ih)[l * 4096 + m] + (dir ? b_hhr : b_hh)[l * 4096 + m];
  }
  if (idx < 128 * 1024) {                     // XPX: x0 = emb[yy[:,0]]
    int b = idx >> 10, k = idx & 1023;
    int e = yy[b * NT];
    float v = emb[(size_t)e * 1024 + k];
    unsigned short h, lo; split_bf(v, h, lo);
    size_t off = ((size_t)(k >> 5) * 8 + (b >> 4)) * 1024
               + ((b & 15) + 16 * ((k >> 3) & 3)) * 8 + (k & 7);
    xpx[off] = h; xpx[off + 512] = lo;
  }
  if (idx < NB) ended[idx] = 0;
}

// ---------------- one-time weight pre-split into A-frag layout ----------------
// WP[((ld*256+mtile)*64+ktile)*1024 + plane*512 + l*8 + r], ld = layer*2+dir
// concat-K per (layer,dir): k<1024 -> W_ih cols, k>=1024 -> W_hh cols (k-1024)
__global__ void k_packW(const float* W_ih, const float* W_hh,
                        const float* W_ihr, const float* W_hhr,
                        unsigned short* WP)
{
  int idx = blockIdx.x * 256 + threadIdx.x;   // 16384 blocks -> 4,194,304
  int l = idx & 63;
  int frag = idx >> 6;                        // [0, 65536)
  int ktile = frag & 63;
  int mtile = (frag >> 6) & 255;
  int ld = frag >> 14;
  int layer = ld >> 1, dir = ld & 1;
  int m = mtile * 16 + (l & 15);
  int kg = ktile * 32 + (l >> 4) * 8;
  const float* base;
  if (kg < 1024) base = (dir ? W_ihr : W_ih) + ((size_t)layer * 4096 + m) * 1024 + kg;
  else           base = (dir ? W_hhr : W_hh) + ((size_t)layer * 4096 + m) * 1024 + (kg - 1024);
  float4 a0 = *(const float4*)base, a1 = *(const float4*)(base + 4);
  s8v hi, lo; cvt8(a0, a1, hi, lo);
  unsigned short* outp = WP + (size_t)frag * 1024 + l * 8;
  *(s8v*)outp = hi;
  *(s8v*)(outp + 512) = lo;
}

// ---------------- main cell GEMM via split-bf16 MFMA, in-block full-K ----------------
// z[m=4096][b=128] = W[m][K=2048] * X[K][b].
// Grid (128, 2dir), 512 thr = 8 waves; block owns 32 m-rows x 128 b x full K.
// Wave w = K-chunk w*256..: per wave 2mt x 8bt x 8kt x 3 = 384 MFMA.
// Epilogue: 5-barrier LDS tree (64KB) reduces 8 wave-partials; single z write.
__device__ __forceinline__ void red_write(float* red, int slot, int l, const f4v (&acc)[2][8])
{
  #pragma unroll
  for (int mt = 0; mt < 2; mt++)
    #pragma unroll
    for (int bt = 0; bt < 8; bt++)
      *(f4v*)&red[(size_t)slot * 4096 + (mt * 8 + bt) * 256 + l * 4] = acc[mt][bt];
}
__device__ __forceinline__ void red_add(const float* red, int slot, int l, f4v (&acc)[2][8])
{
  #pragma unroll
  for (int mt = 0; mt < 2; mt++)
    #pragma unroll
    for (int bt = 0; bt < 8; bt++)
      acc[mt][bt] += *(const f4v*)&red[(size_t)slot * 4096 + (mt * 8 + bt) * 256 + l * 4];
}

template<int PACKED>
__global__ __launch_bounds__(512, 2) void k_gemm(GMF d, float* z)
{
  const int mb = blockIdx.x, dir = blockIdx.y;
  const int tid = threadIdx.x, l = tid & 63, w = tid >> 6;   // w = K-chunk 0..7
  const int m0 = mb * 32;
  const int lr = l & 15, lk = l >> 4;
  __shared__ __align__(16) float red[4 * 4096];              // 64 KB

  f4v acc[2][8];
  #pragma unroll
  for (int mt = 0; mt < 2; mt++)
    #pragma unroll
    for (int bt = 0; bt < 8; bt++)
      acc[mt][bt] = (f4v)(0.0f);

  const unsigned short* Bb = d.Bp[dir * 8 + w] + l * 8;

  if (PACKED) {
    const unsigned short* Wb = d.Wp[dir]
        + (((size_t)(mb * 2) * 64 + w * 8) << 10) + l * 8;
    s8v whc[2], wlc[2];
    #pragma unroll
    for (int mt = 0; mt < 2; mt++) {
      const unsigned short* p = Wb + ((size_t)(mt * 64) << 10);
      whc[mt] = *(const s8v*)p; wlc[mt] = *(const s8v*)(p + 512);
    }
    #pragma unroll 1
    for (int kk = 0; kk < 8; kk++) {
      s8v bh[8], bl[8];
      #pragma unroll
      for (int bt = 0; bt < 8; bt++) {
        const unsigned short* p = Bb + ((size_t)(kk * 8 + bt) << 10);
        bh[bt] = *(const s8v*)p; bl[bt] = *(const s8v*)(p + 512);
      }
      s8v whn[2], wln[2];
      if (kk < 7) {
        #pragma unroll
        for (int mt = 0; mt < 2; mt++) {
          const unsigned short* p = Wb + ((size_t)(mt * 64 + kk + 1) << 10);
          whn[mt] = *(const s8v*)p; wln[mt] = *(const s8v*)(p + 512);
        }
      }
      #pragma unroll
      for (int mt = 0; mt < 2; mt++)
        #pragma unroll
        for (int bt = 0; bt < 8; bt++) {
          acc[mt][bt] = __builtin_amdgcn_mfma_f32_16x16x32_bf16(whc[mt], bh[bt], acc[mt][bt], 0, 0, 0);
          acc[mt][bt] = __builtin_amdgcn_mfma_f32_16x16x32_bf16(whc[mt], bl[bt], acc[mt][bt], 0, 0, 0);
          acc[mt][bt] = __builtin_amdgcn_mfma_f32_16x16x32_bf16(wlc[mt], bh[bt], acc[mt][bt], 0, 0, 0);
        }
      if (kk < 7) {
        whc[0] = whn[0]; whc[1] = whn[1];
        wlc[0] = wln[0]; wlc[1] = wln[1];
      }
    }
  } else {
    const float* Wb = d.W[dir * 8 + w] + (size_t)(m0 + lr) * 1024 + lk * 8;
    float4 ac[2][2];
    #pragma unroll
    for (int mt = 0; mt < 2; mt++) {
      ac[mt][0] = *(const float4*)(Wb + (size_t)mt * 16384);
      ac[mt][1] = *(const float4*)(Wb + (size_t)mt * 16384 + 4);
    }
    #pragma unroll 1
    for (int kk = 0; kk < 8; kk++) {
      s8v bh[8], bl[8];
      #pragma unroll
      for (int bt = 0; bt < 8; bt++) {
        const unsigned short* p = Bb + ((size_t)(kk * 8 + bt) << 10);
        bh[bt] = *(const s8v*)p; bl[bt] = *(const s8v*)(p + 512);
      }
      float4 an[2][2];
      if (kk < 7) {
        #pragma unroll
        for (int mt = 0; mt < 2; mt++) {
          an[mt][0] = *(const float4*)(Wb + (size_t)mt * 16384 + (kk + 1) * 32);
          an[mt][1] = *(const float4*)(Wb + (size_t)mt * 16384 + (kk + 1) * 32 + 4);
        }
      }
      #pragma unroll
      for (int mt = 0; mt < 2; mt++) {
        s8v wh, wl;
        cvt8(ac[mt][0], ac[mt][1], wh, wl);
        #pragma unroll
        for (int bt = 0; bt < 8; bt++) {
          acc[mt][bt] = __builtin_amdgcn_mfma_f32_16x16x32_bf16(wh, bh[bt], acc[mt][bt], 0, 0, 0);
          acc[mt][bt] = __builtin_amdgcn_mfma_f32_16x16x32_bf16(wh, bl[bt], acc[mt][bt], 0, 0, 0);
          acc[mt][bt] = __builtin_amdgcn_mfma_f32_16x16x32_bf16(wl, bh[bt], acc[mt][bt], 0, 0, 0);
        }
      }
      if (kk < 7) {
        #pragma unroll
        for (int mt = 0; mt < 2; mt++) { ac[mt][0] = an[mt][0]; ac[mt][1] = an[mt][1]; }
      }
    }
  }

  // ---- in-block K reduction: 8 -> 4 -> 2 -> store ----
  if (w >= 4) red_write(red, w - 4, l, acc);
  __syncthreads();
  if (w < 4) red_add(red, w, l, acc);
  __syncthreads();
  if (w == 2 || w == 3) red_write(red, w - 2, l, acc);
  __syncthreads();
  if (w < 2) red_add(red, w, l, acc);
  __syncthreads();
  if (w < 2) red_write(red, w, l, acc);
  __syncthreads();
  float* zb = z + (size_t)dir * 4096 * 128;
  #pragma unroll
  for (int vi = 0; vi < 2; vi++) {
    int v = tid + vi * 512;
    f4v s = *(const f4v*)&red[(size_t)v * 4];
    s += *(const f4v*)&red[(size_t)4096 + (size_t)v * 4];
    int frag = v >> 6, lane = v & 63;
    int mt = frag >> 3, bt = frag & 7;
    int m = m0 + mt * 16 + (lane >> 4) * 4;
    int b = bt * 16 + (lane & 15);
    #pragma unroll
    for (int r = 0; r < 4; r++)
      zb[(size_t)(m + r) * 128 + b] = s[r];
  }
}

// ---------------- gates: read z (+bias) -> h, c; pack h frags ----------------
__global__ void k_gates(const float* z, const float* bias, float* c,
                        unsigned short* xph, int ktile0, float* hB)
{
  int t = threadIdx.x;
  int idx = blockIdx.x * 256 + t;
  int n = idx >> 5, cc = (idx & 31) << 2;
  int dir = blockIdx.y;
  float4 g[4];
  #pragma unroll
  for (int gg = 0; gg < 4; gg++) {
    int row = gg * 1024 + n;
    float4 s = *(const float4*)(z + ((size_t)dir * 4096 + row) * 128 + cc);
    float b = bias[dir * 4096 + row];
    s.x += b; s.y += b; s.z += b; s.w += b;
    g[gg] = s;
  }
  float* cp = c + ((size_t)dir * 1024 + n) * 128 + cc;
  float4 cold = *(float4*)cp;
  float4 cn, hn;
  cn.x = sigmoid_stable(g[1].x) * cold.x + sigmoid_stable(g[0].x) * tanhf(g[2].x);
  cn.y = sigmoid_stable(g[1].y) * cold.y + sigmoid_stable(g[0].y) * tanhf(g[2].y);
  cn.z = sigmoid_stable(g[1].z) * cold.z + sigmoid_stable(g[0].z) * tanhf(g[2].z);
  cn.w = sigmoid_stable(g[1].w) * cold.w + sigmoid_stable(g[0].w) * tanhf(g[2].w);
  hn.x = sigmoid_stable(g[3].x) * tanhf(cn.x);
  hn.y = sigmoid_stable(g[3].y) * tanhf(cn.y);
  hn.z = sigmoid_stable(g[3].z) * tanhf(cn.z);
  hn.w = sigmoid_stable(g[3].w) * tanhf(cn.w);
  *(float4*)cp = cn;
  size_t fo = ((size_t)(dir * 64 + ktile0 + (n >> 5)) * 8 + (cc >> 4)) * 1024
            + ((cc & 15) + 16 * ((n >> 3) & 3)) * 8 + (n & 7);
  const float* hv = &hn.x;
  #pragma unroll
  for (int j = 0; j < 4; j++) {
    unsigned short h, lo; split_bf(hv[j], h, lo);
    xph[fo + j * 8] = h;
    xph[fo + j * 8 + 512] = lo;
  }
  if (hB)
    *(float4*)(hB + (size_t)dir * (1024 * 128) + (size_t)n * 128 + cc) = hn;
}

// ---------------- FC GEMM (fp32): fcz[kp][b][e] partials of wh @ fc_W.T ----------------
__global__ __launch_bounds__(256) void k_fc(const float* Ht, const float* fc_W, float* fcz)
{
  int et = blockIdx.x, kp = blockIdx.y;
  int e0 = et * 64;
  int k00 = kp * 256;
  __shared__ __align__(16) float in_s[128][36];
  __shared__ __align__(16) float w_s[64][36];
  int t = threadIdx.x, e_sub = t & 7, bg = t >> 3, b0 = bg * 4;
  float acc[8][4] = {};
  for (int kc = 0; kc < 256; kc += 32) {
    #pragma unroll
    for (int i = 0; i < 4; i++) {
      int flat = t + 256 * i, r = flat >> 3, f4i = flat & 7;
      const float* row = Ht + (r >= 64 ? (size_t)NH * NB + (size_t)(r - 64) * 2048
                                       : (size_t)r * 2048);
      float4 v = *(const float4*)(row + k00 + kc + f4i * 4);
      int sw = (f4i ^ (r >> 2)) & 7;
      *(float4*)&in_s[r][sw * 4] = v;
    }
    #pragma unroll
    for (int i = 0; i < 2; i++) {
      int flat = t + 256 * i, r = flat >> 3, f4i = flat & 7;
      *(float4*)&w_s[r][f4i * 4] =
          *(const float4*)(fc_W + (size_t)(e0 + r) * 2048 + k00 + kc + f4i * 4);
    }
    __syncthreads();
    #pragma unroll
    for (int kq = 0; kq < 8; kq++) {
      int ksw = (kq ^ bg) & 7;
      float4 a4[4];
      #pragma unroll
      for (int ib = 0; ib < 4; ib++) a4[ib] = *(const float4*)&in_s[b0 + ib][ksw * 4];
      float4 w4[8];
      #pragma unroll
      for (int je = 0; je < 8; je++) w4[je] = *(const float4*)&w_s[e_sub + 8 * je][kq * 4];
      #pragma unroll
      for (int je = 0; je < 8; je++)
        #pragma unroll
        for (int ib = 0; ib < 4; ib++)
          acc[je][ib] += a4[ib].x * w4[je].x + a4[ib].y * w4[je].y +
                         a4[ib].z * w4[je].z + a4[ib].w * w4[je].w;
    }
    __syncthreads();
  }
  for (int je = 0; je < 8; je++) {
    int e = e0 + e_sub + 8 * je;
    for (int ib = 0; ib < 4; ib++)
      fcz[((size_t)kp * NB + b0 + ib) * NE + e] = acc[je][ib];
  }
}

// ---------------- finalize: logits, override, argmax, pack next x, softmax ----------------
__global__ void k_final(const float* fcz, const float* fc_b, int* ended,
                        float* out, int tstep, const float* emb, unsigned short* xpx)
{
  int b = blockIdx.x;
  int t = threadIdx.x;
  __shared__ float sval[256];
  __shared__ int   sidx[256];
  __shared__ float ssum[256];
  bool end = (ended[b] != 0);
  float v[4];
  int e_base = t * 4;
  float4 vv = *(const float4*)&fc_b[e_base];
  #pragma unroll
  for (int p = 0; p < 8; p++)
    add4(vv, *(const float4*)&fcz[((size_t)p * NB + b) * NE + e_base]);
  v[0] = vv.x; v[1] = vv.y; v[2] = vv.z; v[3] = vv.w;
  if (end) {
    #pragma unroll
    for (int j = 0; j < 4; j++) v[j] = (e_base + j == EOSL) ? 1.f : 0.f;
  }
  float bv = v[0]; int bi = e_base;
  #pragma unroll
  for (int j = 1; j < 4; j++) if (v[j] > bv) { bv = v[j]; bi = e_base + j; }
  sval[t] = bv; sidx[t] = bi;
  __syncthreads();
  for (int s = 128; s > 0; s >>= 1) {
    if (t < s) {
      float ov = sval[t + s]; int oi = sidx[t + s];
      if (ov > sval[t] || (ov == sval[t] && oi < sidx[t])) { sval[t] = ov; sidx[t] = oi; }
    }
    __syncthreads();
  }
  float m = sval[0]; int label = sidx[0];
  {
    int k0 = t * 4;
    float4 e4 = *(const float4*)(emb + (size_t)label * 1024 + k0);
    size_t off = ((size_t)(k0 >> 5) * 8 + (b >> 4)) * 1024
               + ((b & 15) + 16 * ((k0 >> 3) & 3)) * 8 + (k0 & 7);
    ushort4 h4, l4;
    unsigned short hh, ll;
    split_bf(e4.x, hh, ll); h4.x = hh; l4.x = ll;
    split_bf(e4.y, hh, ll); h4.y = hh; l4.y = ll;
    split_bf(e4.z, hh, ll); h4.z = hh; l4.z = ll;
    split_bf(e4.w, hh, ll); h4.w = hh; l4.w = ll;
    *(ushort4*)(xpx + off) = h4;
    *(ushort4*)(xpx + off + 512) = l4;
  }
  float ls = 0.f;
  #pragma unroll
  for (int j = 0; j < 4; j++) { v[j] = expf(v[j] - m); ls += v[j]; }
  ssum[t] = ls;
  __syncthreads();
  for (int s = 128; s > 0; s >>= 1) { if (t < s) ssum[t] += ssum[t + s]; __syncthreads(); }
  float inv = 1.f / ssum[0];
  float* orow = out + ((size_t)b * NT + tstep) * NE + e_base;
  #pragma unroll
  for (int j = 0; j < 4; j++) orow[j] = v[j] * inv;
  if (t == 0) ended[b] = (end || label == EOSL) ? 1 : 0;
}

extern "C" void kernel_launch(void* const* d_in, const int* in_sizes, int n_in,
                              void* d_out, int out_size, void* d_ws, size_t ws_size,
                              hipStream_t stream)
{
  const int*   yy    = (const int*)d_in[0];
  const float* h_t   = (const float*)d_in[1];
  const float* h_tr  = (const float*)d_in[2];
  const float* emb   = (const float*)d_in[4];
  const float* W_ih  = (const float*)d_in[5];
  const float* W_hh  = (const float*)d_in[6];
  const float* b_ih  = (const float*)d_in[7];
  const float* b_hh  = (const float*)d_in[8];
  const float* W_ihr = (const float*)d_in[9];
  const float* W_hhr = (const float*)d_in[10];
  const float* b_ihr = (const float*)d_in[11];
  const float* b_hhr = (const float*)d_in[12];
  const float* c0    = (const float*)d_in[13];
  const float* c0r   = (const float*)d_in[14];
  const float* fc_W  = (const float*)d_in[15];
  const float* fc_b  = (const float*)d_in[16];
  float* out = (float*)d_out;

  float* ws   = (float*)d_ws;
  float* z    = ws + Z_OFF;
  float* call = ws + C_OFF;
  float* Ht   = ws + HT_OFF;
  float* fcz  = ws + FCZ_OFF;
  float* bias = ws + BIAS_OFF;
  int* ended  = (int*)(ws + END_OFF);
  unsigned short* xph = (unsigned short*)(ws + XPH_OFF);
  unsigned short* xpx = (unsigned short*)(ws + XPX_OFF);
  unsigned short* WP  = (unsigned short*)(ws + WP_OFF);
  bool packed = ws_size >= TOTAL_PACK_F * sizeof(float);

  k_init<<<2048, 256, 0, stream>>>(yy, h_t, h_tr, c0, c0r, b_ih, b_hh, b_ihr, b_hhr,
                                   emb, xph, xpx, call, bias, ended);
  if (packed)
    k_packW<<<16384, 256, 0, stream>>>(W_ih, W_hh, W_ihr, W_hhr, WP);

  GMF d0, d1;
  for (int dir = 0; dir < 2; dir++) {
    const float* Wih0 = dir ? W_ihr : W_ih;
    const float* Whh0 = dir ? W_hhr : W_hh;
    const float* Wih1 = Wih0 + (size_t)G4 * NH;
    const float* Whh1 = Whh0 + (size_t)G4 * NH;
    for (int ks = 0; ks < 8; ks++) {
      d0.W[dir * 8 + ks]  = (ks < 4) ? (Wih0 + ks * 256) : (Whh0 + (ks - 4) * 256);
      d0.Bp[dir * 8 + ks] = (ks < 4) ? (xpx + (size_t)(ks * 64) * 1024)
                                     : (xph + (size_t)((dir * 64 + (ks - 4) * 8) * 8) * 1024);
      d1.W[dir * 8 + ks]  = (ks < 4) ? (Wih1 + ks * 256) : (Whh1 + (ks - 4) * 256);
      d1.Bp[dir * 8 + ks] = xph + (size_t)((dir * 64 + ks * 8) * 8) * 1024;
    }
    d0.Wp[dir] = WP + (size_t)(0 * 2 + dir) * 256 * 64 * 1024;
    d1.Wp[dir] = WP + (size_t)(1 * 2 + dir) * 256 * 64 * 1024;
  }

  for (int t = 0; t < NT; t++) {
    if (packed) k_gemm<1><<<dim3(128, 2), 512, 0, stream>>>(d0, z);
    else        k_gemm<0><<<dim3(128, 2), 512, 0, stream>>>(d0, z);
    k_gates<<<dim3(128, 2), 256, 0, stream>>>(z, bias, call, xph, 0, nullptr);
    if (packed) k_gemm<1><<<dim3(128, 2), 512, 0, stream>>>(d1, z);
    else        k_gemm<0><<<dim3(128, 2), 512, 0, stream>>>(d1, z);
    k_gates<<<dim3(128, 2), 256, 0, stream>>>(z, bias + 2 * 4096,
                                              call + (size_t)2 * 1024 * 128, xph, 32, Ht);
    k_fc<<<dim3(16, 8), 256, 0, stream>>>(Ht, fc_W, fcz);
    k_final<<<128, 256, 0, stream>>>(fcz, fc_b, ended, out, t, emb, xpx);
  }
}